// Round 1
// baseline (208.566 us; speedup 1.0000x reference)
//
#include <hip/hip_runtime.h>

// RotatedGridPool: B=4, C=256, H=200, W=176, N=128, G=7
// Output: (B*N, C, G, G) fp32.
//
// R4: L2 locality. Previous grid ((bn=512) fastest, chunk slowest) gives each
// XCD a ~18MB concurrent feature working set vs 4MB L2 -> gathers thrash to L3.
// Changes:
//  - 1-D grid with explicit XCD-aware decode: block g -> xcd = g%8 (HW
//    round-robin), and each XCD walks (b,chunk) groups sequentially, 128
//    ROI-blocks per group. Concurrent working set per XCD ~= 2 groups.
//  - CSPLIT 8 -> 16 (16 channels/block): group footprint = 16ch * 140.8KB
//    = 2.25MB -> ~4.5MB window ~= L2 capacity (was 18MB).
//  - Non-temporal output stores: write-once 25.7MB output stops evicting
//    feature lines from L2.
// Gather structure itself unchanged from the verified R3 kernel (2 x dwordx2
// per output, edge cases folded into 4 precomputed weights, always in-bounds).

constexpr int Bc = 4;
constexpr int Cc = 256;
constexpr int Hc = 200;
constexpr int Wc = 176;
constexpr int Nc = 128;
constexpr int G  = 7;
constexpr int NPTS = G * G;           // 49
constexpr int CSPLIT = 16;            // blocks per ROI (channel splits)
constexpr int CCHUNK = Cc / CSPLIT;   // 16 channels per block
constexpr int ELEMS  = CCHUNK * NPTS; // 784
constexpr int NXCD = 8;
constexpr float MIN_Xf = 0.0f;
constexpr float MIN_Yf = -40.0f;

// 8-byte load with only 4-byte alignment guarantee (x-offset is arbitrary).
struct __attribute__((packed, aligned(4))) f2u { float x, y; };

__global__ __launch_bounds__(256, 8) void rot_grid_pool_kernel(
    const float* __restrict__ feat,       // (B,C,H,W)
    const float* __restrict__ rois,       // (B,N,7)
    const float* __restrict__ voxel_size, // (2,)
    const int*   __restrict__ fms,        // scalar stride
    float* __restrict__ out)              // (B*N, C, G, G)
{
    // ---- XCD-aware decode ----
    // Total blocks = B*N*CSPLIT = 8192. HW dispatch: block g -> XCD g%8.
    // Per XCD: s = g/8 in [0,1024). group = s/128 in [0,8) selects a
    // (b,chunk) pair; roi = s%128. At any time an XCD's resident blocks
    // share one or two (b,chunk) pairs -> feature working set ~<= L2.
    const int g     = blockIdx.x;
    const int xcd   = g & (NXCD - 1);
    const int s     = g >> 3;
    const int group = s >> 7;             // 0..7
    const int roi   = s & 127;            // 0..127
    const int pair  = group * NXCD + xcd; // 0..63  == b*CSPLIT + chunk
    const int b     = pair >> 4;
    const int chunk = pair & (CSPLIT - 1);
    const int bn    = (b << 7) | roi;

    __shared__ int2   s_off[NPTS];        // flat offsets of the two row loads
    __shared__ float4 s_wgt[NPTS];        // weights for r0.x, r0.y, r1.x, r1.y

    const int tid = threadIdx.x;
    if (tid < NPTS) {
        // ---- per-ROI affine theta ----
        const float* roi_p = rois + (size_t)bn * 7;
        const float cx = roi_p[0], cy = roi_p[1];
        const float dx = roi_p[3], dy = roi_p[4];
        const float ang = roi_p[6];
        const float stride = (float)fms[0];
        const float vx = voxel_size[0] * stride;
        const float vy = voxel_size[1] * stride;

        const float x1 = (cx - dx * 0.5f - MIN_Xf) / vx;
        const float x2 = (cx + dx * 0.5f - MIN_Xf) / vx;
        const float y1 = (cy - dy * 0.5f - MIN_Yf) / vy;
        const float y2 = (cy + dy * 0.5f - MIN_Yf) / vy;

        float sina, cosa;
        __sincosf(ang, &sina, &cosa);

        const float wm1 = (float)(Wc - 1);
        const float hm1 = (float)(Hc - 1);
        const float scale1 = (y2 - y1) / fmaxf(x2 - x1, 0.01f);
        const float scale2 = (x2 - x1) / fmaxf(y2 - y1, 0.01f);
        const float t00 = (x2 - x1) / wm1 * cosa;
        const float t01 = (x2 - x1) / wm1 * (-sina) * scale1;
        const float t02 = (x1 + x2 - wm1) / wm1;
        const float t10 = (y2 - y1) / hm1 * sina * scale2;
        const float t11 = (y2 - y1) / hm1 * cosa;
        const float t12 = (y1 + y2 - hm1) / hm1;

        const int row = tid / G;
        const int col = tid - row * G;
        const float xx = (2.0f * (float)col + 1.0f) / (float)G - 1.0f;
        const float yy = (2.0f * (float)row + 1.0f) / (float)G - 1.0f;
        const float gx = t00 * xx + t01 * yy + t02;
        const float gy = t10 * xx + t11 * yy + t12;
        const float ix = ((gx + 1.0f) * (float)Wc - 1.0f) * 0.5f;
        const float iy = ((gy + 1.0f) * (float)Hc - 1.0f) * 0.5f;

        const float x0f = floorf(ix);
        const float y0f = floorf(iy);
        const float wx1 = ix - x0f, wx0 = 1.0f - wx1;
        const float wy1 = iy - y0f, wy0 = 1.0f - wy1;

        const bool vx0 = (x0f >= 0.0f) && (x0f <= wm1);
        const bool vx1 = (x0f + 1.0f >= 0.0f) && (x0f + 1.0f <= wm1);
        const bool vy0 = (y0f >= 0.0f) && (y0f <= hm1);
        const bool vy1 = (y0f + 1.0f >= 0.0f) && (y0f + 1.0f <= hm1);

        const int x0i = (int)x0f;
        const int y0i = (int)y0f;
        const int xs  = min(max(x0i, 0), Wc - 2);   // dwordx2 at xs always in-bounds
        const int yc0 = min(max(y0i, 0), Hc - 1);
        const int yc1 = min(max(y0i + 1, 0), Hc - 1);

        // weights applying to f[xs] (wa) and f[xs+1] (wb), edge cases folded in
        const float wa = ((vx0 && x0i     == xs    ) ? wx0 : 0.0f)
                       + ((vx1 && x0i + 1 == xs    ) ? wx1 : 0.0f);
        const float wb = ((vx0 && x0i     == xs + 1) ? wx0 : 0.0f)
                       + ((vx1 && x0i + 1 == xs + 1) ? wx1 : 0.0f);
        const float rw0 = vy0 ? wy0 : 0.0f;
        const float rw1 = vy1 ? wy1 : 0.0f;

        s_off[tid] = make_int2(yc0 * Wc + xs, yc1 * Wc + xs);
        s_wgt[tid] = make_float4(rw0 * wa, rw0 * wb, rw1 * wa, rw1 * wb);
    }
    __syncthreads();

    const float* __restrict__ fb = feat + ((size_t)b * Cc + chunk * CCHUNK) * (Hc * Wc);
    float* __restrict__ ob = out + ((size_t)bn * Cc + chunk * CCHUNK) * NPTS;

    #pragma unroll
    for (int k = 0; k < 4; ++k) {
        const int e = tid + k * 256;
        if (e < ELEMS) {
            const int c  = e / NPTS;
            const int pt = e - c * NPTS;
            const float* __restrict__ fc = fb + (size_t)c * (Hc * Wc);
            const int2   o = s_off[pt];
            const float4 w = s_wgt[pt];
            const f2u r0 = *(const f2u*)(fc + o.x);
            const f2u r1 = *(const f2u*)(fc + o.y);
            const float v = w.x * r0.x + w.y * r0.y + w.z * r1.x + w.w * r1.y;
            __builtin_nontemporal_store(v, ob + e);
        }
    }
}

extern "C" void kernel_launch(void* const* d_in, const int* in_sizes, int n_in,
                              void* d_out, int out_size, void* d_ws, size_t ws_size,
                              hipStream_t stream) {
    const float* feat = (const float*)d_in[0];
    const float* rois = (const float*)d_in[1];
    const float* vox  = (const float*)d_in[2];
    const int*   fms  = (const int*)d_in[3];
    float* out = (float*)d_out;

    rot_grid_pool_kernel<<<dim3(Bc * Nc * CSPLIT), dim3(256), 0, stream>>>(
        feat, rois, vox, fms, out);
}